// Round 7
// baseline (315.543 us; speedup 1.0000x reference)
//
#include <hip/hip_runtime.h>
#include <hip/hip_bf16.h>

// 3-layer tanh RNN. B=32, T=64, D_IN=10000, H=200, N_CLASSES=2.
//
// R14:
//  * gemm CONFLICT FIX: R13 counters showed 3.44M SQ_LDS_BANK_CONFLICT --
//    fragment reads (16 lanes @ 64B stride -> banks {0,16}) were 16-way
//    conflicted, ~670cy/kstep + 2100cy raw LDS reads vs 390cy MFMA. Fix by
//    REORDERING the packed-W format to fragment order (lane l's 16B unit at
//    tile_base + l*16): ds_read_b128 becomes lane-contiguous = conflict-free
//    by construction; global_load_lds stays a linear copy (no swizzle).
//    A-tile staged in the same fragment order. All sizes unchanged.
//  * rec STORE-DRAIN FIX (minimal text edit to the frozen R7 function):
//    in-loop __syncthreads() drains vmcnt(0) -> ~400cy/step waiting on the
//    Hout store ack nothing reads. Replaced ONLY the two in-loop barriers
//    with lgkmcnt(0)+raw s_barrier (LDS visibility only; HK s05 pattern).
//    Everything else in rnn_rec is byte-identical to R13. If rec regresses
//    to ~66us, revert this edit only.
//  * launch structure from R13 (9 launches, separate reduce/fc).
//  * split-bf16 3-term everywhere: ~fp32 accuracy at bf16 MFMA rate.

typedef __bf16  bf16x8 __attribute__((ext_vector_type(8)));
typedef __bf16  bf16x4 __attribute__((ext_vector_type(4)));
typedef float   f32x4  __attribute__((ext_vector_type(4)));

#define HDIM 200
#define BM 64
#define CHUNK_B 26624   // bytes per packed k-chunk: hi 13 tiles x 1KB, lo same
#define MFMA(a, b, c) __builtin_amdgcn_mfma_f32_16x16x32_bf16(a, b, c, 0, 0, 0)

__device__ __forceinline__ void glds16(const void* g, void* l) {
    __builtin_amdgcn_global_load_lds(
        (const __attribute__((address_space(1))) unsigned int*)g,
        (__attribute__((address_space(3))) unsigned int*)l, 16, 0, 0);
}

// ---- pack W [HDIM x K] fp32 -> chunks in FRAGMENT ORDER ----
// chunk kc = [hi: 13 n-tiles x 64 lanes x 16B][lo: same].
// unit u (16B): isLo = u>=832; u2 = u%832; nt = u2>>6; l = u2&63;
//   row = nt*16 + (l&15); k = kc*32 + (l>>4)*8.
__global__ void pack_all(const float* __restrict__ W0,
                         const float* __restrict__ W1,
                         const float* __restrict__ W2,
                         __bf16* __restrict__ O0,
                         __bf16* __restrict__ O1,
                         __bf16* __restrict__ O2)
{
    const int T0 = 320 * 1664, T1 = 7 * 1664, T2 = 7 * 1664;
    for (int gt = blockIdx.x * blockDim.x + threadIdx.x; gt < T0 + T1 + T2;
         gt += gridDim.x * blockDim.x) {
        const float* W; __bf16* out; int K, g;
        if (gt < T0)           { W = W0; out = O0; K = 10000; g = gt; }
        else if (gt < T0 + T1) { W = W1; out = O1; K = HDIM;  g = gt - T0; }
        else                   { W = W2; out = O2; K = HDIM;  g = gt - T0 - T1; }

        const int kc = g / 1664;
        const int u  = g - kc * 1664;
        const int isLo = (u >= 832);
        const int u2 = isLo ? u - 832 : u;
        const int nt = u2 >> 6;              // n-tile 0..12
        const int l  = u2 & 63;              // lane slot
        const int r  = nt * 16 + (l & 15);   // 0..207
        const int k  = kc * 32 + (l >> 4) * 8;
        bf16x8 v;
        if (r < HDIM && k < K) {             // K % 8 == 0
            const float* p = W + (size_t)r * K + k;
            float4 a = *(const float4*)p, b = *(const float4*)(p + 4);
            float f[8] = {a.x, a.y, a.z, a.w, b.x, b.y, b.z, b.w};
#pragma unroll
            for (int i = 0; i < 8; ++i) {
                __bf16 h = (__bf16)f[i];
                v[i] = isLo ? (__bf16)(f[i] - (float)h) : h;
            }
        } else {
#pragma unroll
            for (int i = 0; i < 8; ++i) v[i] = (__bf16)0.f;
        }
        *(bf16x8*)&out[(size_t)g * 8] = v;
    }
}

// ---- pipelined GEMM: C[m][n] = sum_k A[m][k]*W[n][k] over this block's k ----
// BM=64 (4 Mtiles). 8 waves = 2 M-groups x 4 N-groups (4/3/3/3 ntiles).
// One barrier/kstep. 68 KB LDS -> 2 blocks/CU. Fragment-ordered LDS:
// tile t's fragment for lane l at bf16 offset t*512 + l*8 (conflict-free).
__global__ __launch_bounds__(512, 4)
void gemm_pipe(const float* __restrict__ A, int lda, int K,
               const __bf16* __restrict__ Bpack,
               float* __restrict__ Cbase, int per_split, int ksteps)
{
    __shared__ alignas(16) __bf16 Ab[2][4096];    // [hi 2048 | lo 2048] frag-order
    __shared__ alignas(16) __bf16 Bb[2][13312];   // [hi 6656 | lo 6656] frag-order

    const int tid = threadIdx.x;
    const int kc0 = blockIdx.y * ksteps;
    const int m0  = blockIdx.x * BM;
    float* __restrict__ C = Cbase + (size_t)blockIdx.y * per_split;

    const int wv = tid >> 6, lane = tid & 63;
    const int r16 = lane & 15, kg = lane >> 4;
    const int mg = wv & 1, ng = wv >> 1;
    const int nt0 = ng ? 1 + ng * 3 : 0;        // 0,4,7,10
    const int ntw = ng ? 3 : 4;
    const int fb  = lane * 8;                   // lane's fragment offset (bf16)

    const int a_row = tid >> 3;          // 0..63
    const int a_q   = tid & 7;           // float4 column group
    const float* Arow = A + (size_t)(m0 + a_row) * lda + a_q * 4;
    // A staging slot in fragment order:
    const int a_off = (a_row >> 4) * 512 + ((a_row & 15) + 16 * (a_q >> 1)) * 8
                    + (a_q & 1) * 4;

    f32x4 acc[2][4];
#pragma unroll
    for (int mi = 0; mi < 2; ++mi)
#pragma unroll
        for (int j = 0; j < 4; ++j) acc[mi][j] = (f32x4)0.f;

    float av[4];
    auto loadA = [&](int ks) {
        const int kb = (kc0 + ks) * 32;
        if (kb + a_q * 4 < K) {          // 4-granular, K % 4 == 0
            float4 x0 = *(const float4*)(Arow + kb);
            av[0] = x0.x; av[1] = x0.y; av[2] = x0.z; av[3] = x0.w;
        } else {
#pragma unroll
            for (int i = 0; i < 4; ++i) av[i] = 0.f;
        }
    };
    auto issueB = [&](int ks, int buf) {
        const char* src = (const char*)Bpack + (size_t)(kc0 + ks) * CHUNK_B;
        char* dst = (char*)&Bb[buf][0];
#pragma unroll
        for (int r = 0; r < 3; ++r)
            glds16(src + (r * 512 + tid) * 16, dst + (r * 512 + tid) * 16);
        if (tid < 128)
            glds16(src + (1536 + tid) * 16, dst + (1536 + tid) * 16);
    };

    loadA(0);
    issueB(0, 0);

    for (int ks = 0; ks < ksteps; ++ks) {
        const int cur = ks & 1, nxt = cur ^ 1;
        // commit A regs -> LDS hi/lo in fragment order
        bf16x4 th, tl;
#pragma unroll
        for (int i = 0; i < 4; ++i) {
            __bf16 h = (__bf16)av[i];
            th[i] = h; tl[i] = (__bf16)(av[i] - (float)h);
        }
        *(bf16x4*)&Ab[cur][a_off]        = th;
        *(bf16x4*)&Ab[cur][2048 + a_off] = tl;
        __syncthreads();   // drains glds B(ks)->Bb[cur] + A writes (vmcnt+lgkm)
        if (ks + 1 < ksteps) { issueB(ks + 1, nxt); loadA(ks + 1); }

        const int ao0 = (mg * 2 + 0) * 512 + fb;
        const int ao1 = (mg * 2 + 1) * 512 + fb;
        bf16x8 ah0 = *(const bf16x8*)&Ab[cur][ao0];
        bf16x8 al0 = *(const bf16x8*)&Ab[cur][2048 + ao0];
        bf16x8 ah1 = *(const bf16x8*)&Ab[cur][ao1];
        bf16x8 al1 = *(const bf16x8*)&Ab[cur][2048 + ao1];
#pragma unroll
        for (int j = 0; j < 4; ++j) {
            if (j < ntw) {
                const int bo = (nt0 + j) * 512 + fb;
                bf16x8 bh = *(const bf16x8*)&Bb[cur][bo];
                bf16x8 bl = *(const bf16x8*)&Bb[cur][6656 + bo];
                acc[0][j] = MFMA(al0, bh, acc[0][j]);
                acc[0][j] = MFMA(ah0, bl, acc[0][j]);
                acc[0][j] = MFMA(ah0, bh, acc[0][j]);
                acc[1][j] = MFMA(al1, bh, acc[1][j]);
                acc[1][j] = MFMA(ah1, bl, acc[1][j]);
                acc[1][j] = MFMA(ah1, bh, acc[1][j]);
            }
        }
    }

    // epilogue: C/D layout col=lane&15, row=(lane>>4)*4+reg; plain stores
#pragma unroll
    for (int mi = 0; mi < 2; ++mi) {
        const int rb = m0 + mg * 32 + mi * 16 + kg * 4;
#pragma unroll
        for (int j = 0; j < 4; ++j) {
            if (j < ntw) {
                const int n = (nt0 + j) * 16 + r16;
                if (n < HDIM)
#pragma unroll
                    for (int r = 0; r < 4; ++r)
                        C[(size_t)(rb + r) * HDIM + n] = acc[mi][j][r];
            }
        }
    }
}

// ---- sum 16 k-split partials ----
__global__ void reduce_parts(const float* __restrict__ Pp, float* __restrict__ P)
{
    const int i = blockIdx.x * blockDim.x + threadIdx.x;   // float4 index
    if (i < 102400) {
        float4 s = ((const float4*)Pp)[i];
#pragma unroll
        for (int r = 1; r < 16; ++r) {
            float4 v = ((const float4*)Pp)[(size_t)r * 102400 + i];
            s.x += v.x; s.y += v.y; s.z += v.z; s.w += v.w;
        }
        ((float4*)P)[i] = s;
    }
}

__device__ __forceinline__ float fast_tanh(float x) {
    float e = __expf(-2.f * fabsf(x));
    float r = (1.f - e) / (1.f + e);
    return copysignf(r, x);
}

// LDS-only barrier: waits LDS ops, NOT in-flight global stores (no vmcnt).
__device__ __forceinline__ void bar_lds() {
    asm volatile("s_waitcnt lgkmcnt(0)" ::: "memory");
    __builtin_amdgcn_s_barrier();
}

// ---- recurrence: 1 block/batch; thread owns 4 n x 20 k; w[80] in VGPRs ----
// R13 kernel with ONLY the two in-loop __syncthreads() -> bar_lds().
__global__ __launch_bounds__(512, 1)
void rnn_rec(const float* __restrict__ pre,   // [32][64][200] (GEMM only)
             const float* __restrict__ Whh,   // [200][200]
             const float* __restrict__ bih,
             const float* __restrict__ bhh,
             float* __restrict__ Hout)        // [32][64][200]
{
    const int b   = blockIdx.x;
    const int tid = threadIdx.x;

    __shared__ float preS[64 * HDIM];          // 51.2 KB
    __shared__ float h[HDIM];
    __shared__ float bias[HDIM];
    __shared__ float part[10][HDIM];           // 8 KB

    {   // stage pre slab (coalesced)
        const float4* ps = (const float4*)(pre + (size_t)b * 64 * HDIM);
        float4* pd = (float4*)preS;
        for (int i = tid; i < 3200; i += 512) pd[i] = ps[i];
    }

    const bool act = tid < 500;
    const int g  = tid / 10;            // n-group 0..49
    const int s  = tid - g * 10;        // k-slice 0..9
    const int n0 = g * 4;
    const int k0 = s * 20;

    float w[80];
    if (act) {
#pragma unroll
        for (int j = 0; j < 4; ++j) {
            const float* wr = Whh + (size_t)(n0 + j) * HDIM + k0;
#pragma unroll
            for (int i = 0; i < 5; ++i) {
                float4 v = *(const float4*)(wr + i * 4);
                w[j * 20 + i * 4 + 0] = v.x; w[j * 20 + i * 4 + 1] = v.y;
                w[j * 20 + i * 4 + 2] = v.z; w[j * 20 + i * 4 + 3] = v.w;
            }
        }
    }
    if (tid < HDIM) { bias[tid] = bih[tid] + bhh[tid]; h[tid] = 0.f; }
    __syncthreads();

    for (int t = 0; t < 64; ++t) {
        if (act) {
            float a0 = 0.f, a1 = 0.f, a2 = 0.f, a3 = 0.f;
#pragma unroll
            for (int i = 0; i < 5; ++i) {
                float4 hv = *(const float4*)&h[k0 + i * 4];
                a0 += w[ 0 + i*4]*hv.x + w[ 1 + i*4]*hv.y + w[ 2 + i*4]*hv.z + w[ 3 + i*4]*hv.w;
                a1 += w[20 + i*4]*hv.x + w[21 + i*4]*hv.y + w[22 + i*4]*hv.z + w[23 + i*4]*hv.w;
                a2 += w[40 + i*4]*hv.x + w[41 + i*4]*hv.y + w[42 + i*4]*hv.z + w[43 + i*4]*hv.w;
                a3 += w[60 + i*4]*hv.x + w[61 + i*4]*hv.y + w[62 + i*4]*hv.z + w[63 + i*4]*hv.w;
            }
            float4 pv = make_float4(a0, a1, a2, a3);
            *(float4*)&part[s][n0] = pv;
        }
        bar_lds();
        if (tid < HDIM) {
            float sum = part[0][tid];
#pragma unroll
            for (int r = 1; r < 10; ++r) sum += part[r][tid];
            float v = fast_tanh(sum + preS[t * HDIM + tid] + bias[tid]);
            h[tid] = v;
            Hout[((size_t)b * 64 + t) * HDIM + tid] = v;
        }
        bar_lds();
    }
}

// ---- trivially-correct FC head ----
__global__ void fc_head(const float* __restrict__ Hlast_base,
                        const float* __restrict__ fcw,
                        const float* __restrict__ fcb,
                        float* __restrict__ out)
{
    const int i = threadIdx.x;
    if (i >= 64) return;
    const int b = i >> 1, cls = i & 1;
    const float* hp = Hlast_base + ((size_t)b * 64 + 63) * HDIM;
    const float* fw = fcw + cls * HDIM;
    float s = fcb[cls];
    for (int j = 0; j < HDIM; ++j) s += hp[j] * fw[j];
    out[b * 2 + cls] = s;
}

extern "C" void kernel_launch(void* const* d_in, const int* in_sizes, int n_in,
                              void* d_out, int out_size, void* d_ws, size_t ws_size,
                              hipStream_t stream) {
    const float* x     = (const float*)d_in[0];
    const float* W_ih0 = (const float*)d_in[1];
    const float* W_hh0 = (const float*)d_in[2];
    const float* b_ih0 = (const float*)d_in[3];
    const float* b_hh0 = (const float*)d_in[4];
    const float* W_ih1 = (const float*)d_in[5];
    const float* W_hh1 = (const float*)d_in[6];
    const float* b_ih1 = (const float*)d_in[7];
    const float* b_hh1 = (const float*)d_in[8];
    const float* W_ih2 = (const float*)d_in[9];
    const float* W_hh2 = (const float*)d_in[10];
    const float* b_ih2 = (const float*)d_in[11];
    const float* b_hh2 = (const float*)d_in[12];
    const float* fc_w  = (const float*)d_in[13];
    const float* fc_b  = (const float*)d_in[14];
    float* out = (float*)d_out;

    const size_t PE = (size_t)2048 * HDIM;          // 409600
    float* P     = (float*)d_ws;
    float* Hbuf  = P + PE;
    float* Hbuf2 = Hbuf + PE;
    float* Ppart = Hbuf2 + PE;                      // 16 x 409600
    __bf16* W0p  = (__bf16*)(Ppart + 16 * PE);      // 320 chunks x 13312 bf16
    __bf16* W1p  = W0p + (size_t)320 * 13312;       // 7 chunks
    __bf16* W2p  = W1p + (size_t)7 * 13312;
    // total ws: ~40.0 MB

    // ---- prologue: pack all weights (one launch) ----
    pack_all<<<1024, 256, 0, stream>>>(W_ih0, W_ih1, W_ih2, W0p, W1p, W2p);

    // ---- layer 0: K=10000, 16-way k-split (20 ksteps each), partials ----
    gemm_pipe<<<dim3(32, 16), 512, 0, stream>>>(x, 10000, 10000, W0p, Ppart, (int)PE, 20);
    reduce_parts<<<400, 256, 0, stream>>>(Ppart, P);
    rnn_rec<<<32, 512, 0, stream>>>(P, W_hh0, b_ih0, b_hh0, Hbuf);

    // ---- layer 1: K=200, single split, direct store ----
    gemm_pipe<<<dim3(32, 1), 512, 0, stream>>>(Hbuf, HDIM, HDIM, W1p, P, (int)PE, 7);
    rnn_rec<<<32, 512, 0, stream>>>(P, W_hh1, b_ih1, b_hh1, Hbuf2);

    // ---- layer 2 ----
    gemm_pipe<<<dim3(32, 1), 512, 0, stream>>>(Hbuf2, HDIM, HDIM, W2p, P, (int)PE, 7);
    rnn_rec<<<32, 512, 0, stream>>>(P, W_hh2, b_ih2, b_hh2, Hbuf);

    // ---- FC head ----
    fc_head<<<1, 64, 0, stream>>>(Hbuf, fc_w, fc_b, out);
}